// Round 15
// baseline (311.098 us; speedup 1.0000x reference)
//
#include <hip/hip_runtime.h>
#include <hip/hip_bf16.h>

#define CH 64          // IN_C = HID_C = OUT_C = 64
#define BSH 9          // bucket shift: 512 nodes/bucket
#define CHUNK 16384    // edges per block in hist/scatter passes (1024 thr x 16)
#define MAXB 10240     // LDS col buffer (edges/bucket ~8163 +- 90)

// ---------- CSR build: two-level counting sort, all atomics in LDS ----------

__global__ __launch_bounds__(1024)
void coarse_hist_kernel(const int* __restrict__ dst, int* __restrict__ blockHist,
                        int E, int nb) {
    __shared__ int h[256];
    int t = threadIdx.x;
    for (int i = t; i < nb; i += 1024) h[i] = 0;
    __syncthreads();
    int base = blockIdx.x * CHUNK + t * 16;
#pragma unroll
    for (int j = 0; j < 16; j += 4) {
        int e = base + j;
        if (e + 3 < E) {
            int4 d = *(const int4*)(dst + e);
            atomicAdd(&h[d.x >> BSH], 1);
            atomicAdd(&h[d.y >> BSH], 1);
            atomicAdd(&h[d.z >> BSH], 1);
            atomicAdd(&h[d.w >> BSH], 1);
        } else {
            for (int k = e; k < E && k < e + 4; ++k) atomicAdd(&h[dst[k] >> BSH], 1);
        }
    }
    __syncthreads();
    for (int i = t; i < nb; i += 1024) blockHist[blockIdx.x * nb + i] = h[i];
}

__global__ __launch_bounds__(256)
void scan_hist_kernel(int* __restrict__ blockHist, int* __restrict__ bucketStart,
                      int nblk, int nb) {
    __shared__ int tots[256];
    __shared__ int scn[257];
    int t = threadIdx.x;
    if (t < nb) {
        int s = 0;
        for (int blk = 0; blk < nblk; ++blk) s += blockHist[blk * nb + t];
        tots[t] = s;
    }
    __syncthreads();
    if (t == 0) {
        int r = 0;
        for (int b = 0; b < nb; ++b) { scn[b] = r; r += tots[b]; }
        scn[nb] = r;
    }
    __syncthreads();
    if (t < nb) {
        int r = scn[t];
        for (int blk = 0; blk < nblk; ++blk) {
            int v = blockHist[blk * nb + t];
            blockHist[blk * nb + t] = r;   // in-place: now absolute base
            r += v;
        }
    }
    if (t <= nb) bucketStart[t] = scn[t];
}

__global__ __launch_bounds__(1024)
void scatter_pairs_kernel(const int* __restrict__ src, const int* __restrict__ dst,
                          const int* __restrict__ blockBase, int2* __restrict__ pairs,
                          int E, int nb) {
    __shared__ int cur[256];
    int t = threadIdx.x;
    for (int i = t; i < nb; i += 1024) cur[i] = blockBase[blockIdx.x * nb + i];
    __syncthreads();
    int base = blockIdx.x * CHUNK + t * 16;
#pragma unroll
    for (int j = 0; j < 16; j += 4) {
        int e = base + j;
        if (e + 3 < E) {
            int4 d = *(const int4*)(dst + e);
            int4 s = *(const int4*)(src + e);
            int p0 = atomicAdd(&cur[d.x >> BSH], 1); pairs[p0] = make_int2(d.x, s.x);
            int p1 = atomicAdd(&cur[d.y >> BSH], 1); pairs[p1] = make_int2(d.y, s.y);
            int p2 = atomicAdd(&cur[d.z >> BSH], 1); pairs[p2] = make_int2(d.z, s.z);
            int p3 = atomicAdd(&cur[d.w >> BSH], 1); pairs[p3] = make_int2(d.w, s.w);
        } else {
            for (int k = e; k < E && k < e + 4; ++k) {
                int d = dst[k];
                int p = atomicAdd(&cur[d >> BSH], 1);
                pairs[p] = make_int2(d, src[k]);
            }
        }
    }
}

__global__ __launch_bounds__(1024)
void bucket_csr_kernel(const int2* __restrict__ pairs, const int* __restrict__ bucketStart,
                       int* __restrict__ col, int* __restrict__ rs, float* __restrict__ dis,
                       int N, int nb) {
    __shared__ int hist[512];
    __shared__ int offs[512];
    __shared__ int cursor[512];
    __shared__ int lcol[MAXB];
    int b = blockIdx.x;
    int t = threadIdx.x;
    int n0 = b << BSH;
    int nn = min(512, N - n0);
    int start = bucketStart[b];
    int endp = bucketStart[b + 1];
    int cnt = endp - start;
    bool big = cnt > MAXB;  // safety fallback: direct (uncoalesced) col writes
    for (int i = t; i < nn; i += 1024) hist[i] = 0;
    __syncthreads();
    for (int i = start + t; i < endp; i += 1024) {
        int2 p = pairs[i];
        atomicAdd(&hist[p.x - n0], 1);
    }
    __syncthreads();
    if (t < 512) offs[t] = (t < nn) ? hist[t] : 0;
    __syncthreads();
    for (int off = 1; off < 512; off <<= 1) {
        int a = (t < 512 && t >= off) ? offs[t - off] : 0;
        __syncthreads();
        if (t < 512) offs[t] += a;
        __syncthreads();
    }
    if (t < nn) {
        int excl = offs[t] - hist[t];          // exclusive scan value
        rs[n0 + t] = start + excl;
        dis[n0 + t] = rsqrtf((float)hist[t] + 1.0f);
        cursor[t] = excl;
    }
    __syncthreads();
    for (int i = start + t; i < endp; i += 1024) {
        int2 p = pairs[i];
        int pos = atomicAdd(&cursor[p.x - n0], 1);
        if (big) col[start + pos] = p.y;
        else lcol[pos] = p.y;
    }
    __syncthreads();
    if (!big) {
        for (int i = t; i < cnt; i += 1024) col[start + i] = lcol[i];
    }
}

// ---------- compute ----------

__device__ inline unsigned pack_bf2(float a, float b) {
    __hip_bfloat162 t;
    t.x = __float2bfloat16(a);
    t.y = __float2bfloat16(b);
    unsigned u;
    __builtin_memcpy(&u, &t, 4);
    return u;
}

// bf16 (as raw u16) -> float: one shift + bitcast
__device__ inline float bfu(unsigned short raw) {
    unsigned w = ((unsigned)raw) << 16;
    float f;
    __builtin_memcpy(&f, &w, 4);
    return f;
}

#define FMA16(xs0, xs1, wa, wb)                                              \
    a00 += (xs0) * (wa).x; a01 += (xs0) * (wa).y;                            \
    a02 += (xs0) * (wa).z; a03 += (xs0) * (wa).w;                            \
    a04 += (xs0) * (wb).x; a05 += (xs0) * (wb).y;                            \
    a06 += (xs0) * (wb).z; a07 += (xs0) * (wb).w;                            \
    a10 += (xs1) * (wa).x; a11 += (xs1) * (wa).y;                            \
    a12 += (xs1) * (wa).z; a13 += (xs1) * (wa).w;                            \
    a14 += (xs1) * (wb).x; a15 += (xs1) * (wb).y;                            \
    a16 += (xs1) * (wb).z; a17 += (xs1) * (wb).w;

// GEMM: 2 rows x 8 cols per thread, ALL NAMED SCALARS (hipcc does not SROA
// private arrays -> scratch).  __launch_bounds__(256,4) + unroll-4: cap 128
// VGPR (unbounded build hits 256 VGPR -> 2 waves/SIMD -> 99% latency stall).
__global__ __launch_bounds__(256, 4)
void gemm64_scaled_kernel(const float* __restrict__ X, const float* __restrict__ W,
                          const float* __restrict__ dis,
                          __hip_bfloat16* __restrict__ Y, int n) {
    __shared__ float Ws[CH * CH];
    {
        float4* w4 = (float4*)Ws;
        const float4* g4 = (const float4*)W;
        for (int i = threadIdx.x; i < CH * CH / 4; i += 256) w4[i] = g4[i];
    }
    __syncthreads();
    int t = threadIdx.x;
    int cbase = (t & 7) * 8;
    int r0 = blockIdx.x * 64 + (t >> 3) * 2;
    if (r0 >= n) return;
    int r1c = min(r0 + 1, n - 1);
    const float4* p0 = (const float4*)(X + (size_t)r0 * CH);
    const float4* p1 = (const float4*)(X + (size_t)r1c * CH);

    float a00 = 0.f, a01 = 0.f, a02 = 0.f, a03 = 0.f;
    float a04 = 0.f, a05 = 0.f, a06 = 0.f, a07 = 0.f;
    float a10 = 0.f, a11 = 0.f, a12 = 0.f, a13 = 0.f;
    float a14 = 0.f, a15 = 0.f, a16 = 0.f, a17 = 0.f;

#pragma unroll 4
    for (int k4 = 0; k4 < CH / 4; ++k4) {
        float4 xa = p0[k4];
        float4 xb = p1[k4];
        const float* wr = &Ws[(k4 * 4) * CH + cbase];
        float4 wa, wb;
        wa = *(const float4*)(wr);
        wb = *(const float4*)(wr + 4);
        FMA16(xa.x, xb.x, wa, wb)
        wa = *(const float4*)(wr + CH);
        wb = *(const float4*)(wr + CH + 4);
        FMA16(xa.y, xb.y, wa, wb)
        wa = *(const float4*)(wr + 2 * CH);
        wb = *(const float4*)(wr + 2 * CH + 4);
        FMA16(xa.z, xb.z, wa, wb)
        wa = *(const float4*)(wr + 3 * CH);
        wb = *(const float4*)(wr + 3 * CH + 4);
        FMA16(xa.w, xb.w, wa, wb)
    }

    float d0 = dis[r0];
    uint4 pk;
    pk.x = pack_bf2(a00 * d0, a01 * d0);
    pk.y = pack_bf2(a02 * d0, a03 * d0);
    pk.z = pack_bf2(a04 * d0, a05 * d0);
    pk.w = pack_bf2(a06 * d0, a07 * d0);
    *(uint4*)(Y + (size_t)r0 * CH + cbase) = pk;
    if (r0 + 1 < n) {
        float d1 = dis[r0 + 1];
        pk.x = pack_bf2(a10 * d1, a11 * d1);
        pk.y = pack_bf2(a12 * d1, a13 * d1);
        pk.z = pack_bf2(a14 * d1, a15 * d1);
        pk.w = pack_bf2(a16 * d1, a17 * d1);
        *(uint4*)(Y + (size_t)(r0 + 1) * CH + cbase) = pk;
    }
}

// Scalar-address (saddr) gather body: wid_u is readfirstlane'd -> the
// compiler's uniformity analysis turns rs[wid_u] and col[e] into s_loads
// (scalar pipe, s_load_dwordx8 = 8 edge indices/instr) and each gather into
// global_load_ushort with SCALAR base + fixed vector offset (lane*2).  The
// per-edge 64-bit address math moves to the SALU (parallel issue pipe) —
// R14's VALUBusy 53% was dominated by vector address arithmetic.  Full wave
// per edge (lane = channel, 2B/lane = one 128B line); no half-split, no
// shfl, no fold, no divergence hazard.
#define GATHER_SADDR_BODY(XWS)                                                \
    int beg = rs[wid_u];                                                      \
    int end = (wid_u + 1 < n) ? rs[wid_u + 1] : E;                            \
    float acc0 = 0.f, acc1 = 0.f;                                             \
    int e = beg;                                                              \
    for (; e + 8 <= end; e += 8) {                                            \
        int s0 = col[e + 0];                                                  \
        int s1 = col[e + 1];                                                  \
        int s2 = col[e + 2];                                                  \
        int s3 = col[e + 3];                                                  \
        int s4 = col[e + 4];                                                  \
        int s5 = col[e + 5];                                                  \
        int s6 = col[e + 6];                                                  \
        int s7 = col[e + 7];                                                  \
        float v0 = bfu((XWS)[(size_t)s0 * CH + lane]);                        \
        float v1 = bfu((XWS)[(size_t)s1 * CH + lane]);                        \
        float v2 = bfu((XWS)[(size_t)s2 * CH + lane]);                        \
        float v3 = bfu((XWS)[(size_t)s3 * CH + lane]);                        \
        float v4 = bfu((XWS)[(size_t)s4 * CH + lane]);                        \
        float v5 = bfu((XWS)[(size_t)s5 * CH + lane]);                        \
        float v6 = bfu((XWS)[(size_t)s6 * CH + lane]);                        \
        float v7 = bfu((XWS)[(size_t)s7 * CH + lane]);                        \
        acc0 += (v0 + v1) + (v2 + v3);                                        \
        acc1 += (v4 + v5) + (v6 + v7);                                        \
    }                                                                         \
    for (; e < end; ++e)                                                      \
        acc0 += bfu((XWS)[(size_t)col[e] * CH + lane]);                       \
    float acc = acc0 + acc1;

// Layer-1 gather: h[wid, lane] fp32 (4B/lane, dense 256B per wave).
__global__ __launch_bounds__(256)
void gather_pair_kernel(const unsigned short* __restrict__ xws, const int* __restrict__ col,
                        const int* __restrict__ rs, const float* __restrict__ dis,
                        const float* __restrict__ b1, float* __restrict__ h,
                        int n, int E) {
    int wid = blockIdx.x * 4 + (threadIdx.x >> 6);
    int lane = threadIdx.x & 63;
    if (wid >= n) return;
    int wid_u = __builtin_amdgcn_readfirstlane(wid);

    GATHER_SADDR_BODY(xws)

    float dd = dis[wid_u];
    float self = bfu(xws[(size_t)wid_u * CH + lane]);
    float hv = fmaxf(dd * (acc + self) + b1[lane], 0.f);
    h[(size_t)wid_u * CH + lane] = hv;
}

// Layer-2 gather + relu + per-block LN partials.
__global__ __launch_bounds__(256)
void gather_stats_kernel(const unsigned short* __restrict__ xws, const int* __restrict__ col,
                         const int* __restrict__ rs, const float* __restrict__ dis,
                         const float* __restrict__ b2, float* __restrict__ out,
                         int n, int E, float* __restrict__ sums, float* __restrict__ sqs) {
    int wid = blockIdx.x * 4 + (threadIdx.x >> 6);
    int lane = threadIdx.x & 63;
    float v = 0.f;
    if (wid < n) {
        int wid_u = __builtin_amdgcn_readfirstlane(wid);
        GATHER_SADDR_BODY(xws)
        float dd = dis[wid_u];
        float self = bfu(xws[(size_t)wid_u * CH + lane]);
        v = fmaxf(dd * (acc + self) + b2[lane], 0.f);
        out[(size_t)wid_u * CH + lane] = v;
    }
    float s = v, sq = v * v;
#pragma unroll
    for (int off = 32; off > 0; off >>= 1) {
        s += __shfl_down(s, off, 64);
        sq += __shfl_down(sq, off, 64);
    }
    __shared__ float ls[4], lq[4];
    int w = threadIdx.x >> 6;
    if ((threadIdx.x & 63) == 0) { ls[w] = s; lq[w] = sq; }
    __syncthreads();
    if (threadIdx.x == 0) {
        sums[blockIdx.x] = ls[0] + ls[1] + ls[2] + ls[3];
        sqs[blockIdx.x] = lq[0] + lq[1] + lq[2] + lq[3];
    }
}

__global__ void reduce_final_kernel(const float* __restrict__ sums, const float* __restrict__ sqs,
                                    int nb, float n_total, const float* __restrict__ lnw,
                                    const float* __restrict__ lnb, float* __restrict__ so) {
    float s = 0.0f, sq = 0.0f;
    for (int i = threadIdx.x; i < nb; i += 1024) { s += sums[i]; sq += sqs[i]; }
#pragma unroll
    for (int off = 32; off > 0; off >>= 1) {
        s += __shfl_down(s, off, 64);
        sq += __shfl_down(sq, off, 64);
    }
    __shared__ float ls[16], lq[16];
    int w = threadIdx.x >> 6;
    if ((threadIdx.x & 63) == 0) { ls[w] = s; lq[w] = sq; }
    __syncthreads();
    if (threadIdx.x == 0) {
        float ts = 0.0f, tq = 0.0f;
        for (int i = 0; i < 16; ++i) { ts += ls[i]; tq += lq[i]; }
        float mean = ts / n_total;
        float var = tq / n_total - mean * mean;
        float scale = rsqrtf(var + 1e-5f) * lnw[0];
        so[0] = scale;
        so[1] = lnb[0] - mean * scale;
    }
}

__global__ void norm_kernel(float* __restrict__ x, int n4, const float* __restrict__ so) {
    int i = blockIdx.x * blockDim.x + threadIdx.x;
    if (i >= n4) return;
    float scale = so[0], off = so[1];
    float4* x4 = (float4*)x;
    float4 v = x4[i];
    v.x = v.x * scale + off;
    v.y = v.y * scale + off;
    v.z = v.z * scale + off;
    v.w = v.w * scale + off;
    x4[i] = v;
}

extern "C" void kernel_launch(void* const* d_in, const int* in_sizes, int n_in,
                              void* d_out, int out_size, void* d_ws, size_t ws_size,
                              hipStream_t stream) {
    const float* X   = (const float*)d_in[0];
    const int*   edg = (const int*)d_in[1];   // [2,E]: src row then dst row
    const float* W1  = (const float*)d_in[2];
    const float* b1  = (const float*)d_in[3];
    const float* W2  = (const float*)d_in[4];
    const float* b2  = (const float*)d_in[5];
    const float* lnw = (const float*)d_in[6];
    const float* lnb = (const float*)d_in[7];
    float* out = (float*)d_out;

    const int N  = in_sizes[0] / CH;   // 100000
    const int E  = in_sizes[1] / 2;    // 1600000
    const int NC = N * CH;             // 6.4M
    const int nNodeBlk = (N + 3) / 4;  // 25000 (4 nodes / block)
    const int nb = (N + 511) >> BSH;   // 196 buckets
    const int nblkE = (E + CHUNK - 1) / CHUNK;  // 98 edge-chunk blocks

    const int* srcp = edg;
    const int* dstp = edg + E;

    // workspace layout (4B units).  pairs (E int2) is dead after bucket_csr;
    // h (NC floats) overlays it.
    int*   col   = (int*)d_ws;                          // E
    int*   rs    = col + E;                             // N
    float* dis   = (float*)(rs + N);                    // N
    __hip_bfloat16* xws1 = (__hip_bfloat16*)(dis + N);  // NC bf16
    __hip_bfloat16* xws2 = xws1 + NC;                   // NC bf16
    float* h     = (float*)(xws2 + NC);                 // NC floats
    int2*  pairs = (int2*)h;                            // E int2 (dead before h live)
    int*   bHist = (int*)(h + NC);                      // nblkE*nb
    int*   bStart= bHist + nblkE * nb;                  // nb+1
    float* sums  = (float*)(bStart + nb + 1);           // nNodeBlk
    float* sqs   = sums + nNodeBlk;                     // nNodeBlk
    float* so    = sqs + nNodeBlk;                      // 2 {scale, offset}

    const int B = 256;
    const int nGemmBlk = (N + 63) / 64;                 // 1563

    // ---- CSR build (no global atomics, no memset) ----
    coarse_hist_kernel<<<nblkE, 1024, 0, stream>>>(dstp, bHist, E, nb);
    scan_hist_kernel<<<1, 256, 0, stream>>>(bHist, bStart, nblkE, nb);
    scatter_pairs_kernel<<<nblkE, 1024, 0, stream>>>(srcp, dstp, bHist, pairs, E, nb);
    bucket_csr_kernel<<<nb, 1024, 0, stream>>>(pairs, bStart, col, rs, dis, N, nb);
    // rs = row_start; row i spans [rs[i], rs[i+1]), last row ends at E

    // ---- layer 1 ----
    gemm64_scaled_kernel<<<nGemmBlk, B, 0, stream>>>(X, W1, dis, xws1, N);
    gather_pair_kernel<<<nNodeBlk, B, 0, stream>>>((const unsigned short*)xws1, col, rs, dis,
                                                   b1, h, N, E);

    // ---- layer 2 ----
    gemm64_scaled_kernel<<<nGemmBlk, B, 0, stream>>>(h, W2, dis, xws2, N);
    gather_stats_kernel<<<nNodeBlk, B, 0, stream>>>((const unsigned short*)xws2, col, rs, dis,
                                                    b2, out, N, E, sums, sqs);

    // ---- graph layernorm ----
    reduce_final_kernel<<<1, 1024, 0, stream>>>(sums, sqs, nNodeBlk, (float)NC, lnw, lnb, so);
    norm_kernel<<<(NC / 4 + B - 1) / B, B, 0, stream>>>(out, NC / 4, so);
}

// Round 16
// 295.239 us; speedup vs baseline: 1.0537x; 1.0537x over previous
//
#include <hip/hip_runtime.h>
#include <hip/hip_bf16.h>

#define CH 64          // IN_C = HID_C = OUT_C = 64
#define BSH 9          // bucket shift: 512 nodes/bucket
#define CHUNK 16384    // edges per block in hist/scatter passes (1024 thr x 16)
#define MAXB 10240     // LDS col buffer (edges/bucket ~8163 +- 90)
// pairs packing: src < 2^17 (N=100000 <= 131072), dstLocal < 2^9 -> 26 bits

// ---------- CSR build: two-level counting sort, all atomics in LDS ----------

__global__ __launch_bounds__(1024)
void coarse_hist_kernel(const int* __restrict__ dst, int* __restrict__ blockHist,
                        int E, int nb) {
    __shared__ int h[256];
    int t = threadIdx.x;
    for (int i = t; i < nb; i += 1024) h[i] = 0;
    __syncthreads();
    int base = blockIdx.x * CHUNK + t * 16;
#pragma unroll
    for (int j = 0; j < 16; j += 4) {
        int e = base + j;
        if (e + 3 < E) {
            int4 d = *(const int4*)(dst + e);
            atomicAdd(&h[d.x >> BSH], 1);
            atomicAdd(&h[d.y >> BSH], 1);
            atomicAdd(&h[d.z >> BSH], 1);
            atomicAdd(&h[d.w >> BSH], 1);
        } else {
            for (int k = e; k < E && k < e + 4; ++k) atomicAdd(&h[dst[k] >> BSH], 1);
        }
    }
    __syncthreads();
    for (int i = t; i < nb; i += 1024) blockHist[blockIdx.x * nb + i] = h[i];
}

__global__ __launch_bounds__(256)
void scan_hist_kernel(int* __restrict__ blockHist, int* __restrict__ bucketStart,
                      int nblk, int nb) {
    __shared__ int tots[256];
    __shared__ int scn[257];
    int t = threadIdx.x;
    if (t < nb) {
        int s = 0;
        for (int blk = 0; blk < nblk; ++blk) s += blockHist[blk * nb + t];
        tots[t] = s;
    }
    __syncthreads();
    if (t == 0) {
        int r = 0;
        for (int b = 0; b < nb; ++b) { scn[b] = r; r += tots[b]; }
        scn[nb] = r;
    }
    __syncthreads();
    if (t < nb) {
        int r = scn[t];
        for (int blk = 0; blk < nblk; ++blk) {
            int v = blockHist[blk * nb + t];
            blockHist[blk * nb + t] = r;   // in-place: now absolute base
            r += v;
        }
    }
    if (t <= nb) bucketStart[t] = scn[t];
}

// pairs entry: (dstLocal << 17) | src  (one 4B word/edge — halves the
// random-region write traffic vs int2)
__global__ __launch_bounds__(1024)
void scatter_pairs_kernel(const int* __restrict__ src, const int* __restrict__ dst,
                          const int* __restrict__ blockBase, unsigned* __restrict__ pairs,
                          int E, int nb) {
    __shared__ int cur[256];
    int t = threadIdx.x;
    for (int i = t; i < nb; i += 1024) cur[i] = blockBase[blockIdx.x * nb + i];
    __syncthreads();
    int base = blockIdx.x * CHUNK + t * 16;
#pragma unroll
    for (int j = 0; j < 16; j += 4) {
        int e = base + j;
        if (e + 3 < E) {
            int4 d = *(const int4*)(dst + e);
            int4 s = *(const int4*)(src + e);
            int p0 = atomicAdd(&cur[d.x >> BSH], 1);
            pairs[p0] = ((unsigned)(d.x & 511) << 17) | (unsigned)s.x;
            int p1 = atomicAdd(&cur[d.y >> BSH], 1);
            pairs[p1] = ((unsigned)(d.y & 511) << 17) | (unsigned)s.y;
            int p2 = atomicAdd(&cur[d.z >> BSH], 1);
            pairs[p2] = ((unsigned)(d.z & 511) << 17) | (unsigned)s.z;
            int p3 = atomicAdd(&cur[d.w >> BSH], 1);
            pairs[p3] = ((unsigned)(d.w & 511) << 17) | (unsigned)s.w;
        } else {
            for (int k = e; k < E && k < e + 4; ++k) {
                int d = dst[k];
                int p = atomicAdd(&cur[d >> BSH], 1);
                pairs[p] = ((unsigned)(d & 511) << 17) | (unsigned)src[k];
            }
        }
    }
}

__global__ __launch_bounds__(1024)
void bucket_csr_kernel(const unsigned* __restrict__ pairs, const int* __restrict__ bucketStart,
                       int* __restrict__ col, int* __restrict__ rs, float* __restrict__ dis,
                       int N, int nb) {
    __shared__ int hist[512];
    __shared__ int offs[512];
    __shared__ int cursor[512];
    __shared__ int lcol[MAXB];
    int b = blockIdx.x;
    int t = threadIdx.x;
    int n0 = b << BSH;
    int nn = min(512, N - n0);
    int start = bucketStart[b];
    int endp = bucketStart[b + 1];
    int cnt = endp - start;
    bool big = cnt > MAXB;  // safety fallback: direct (uncoalesced) col writes
    for (int i = t; i < nn; i += 1024) hist[i] = 0;
    __syncthreads();
    for (int i = start + t; i < endp; i += 1024) {
        unsigned p = pairs[i];
        atomicAdd(&hist[p >> 17], 1);
    }
    __syncthreads();
    if (t < 512) offs[t] = (t < nn) ? hist[t] : 0;
    __syncthreads();
    for (int off = 1; off < 512; off <<= 1) {
        int a = (t < 512 && t >= off) ? offs[t - off] : 0;
        __syncthreads();
        if (t < 512) offs[t] += a;
        __syncthreads();
    }
    if (t < nn) {
        int excl = offs[t] - hist[t];          // exclusive scan value
        rs[n0 + t] = start + excl;
        dis[n0 + t] = rsqrtf((float)hist[t] + 1.0f);
        cursor[t] = excl;
    }
    __syncthreads();
    for (int i = start + t; i < endp; i += 1024) {
        unsigned p = pairs[i];
        int pos = atomicAdd(&cursor[p >> 17], 1);
        int sv = (int)(p & 0x1FFFFu);
        if (big) col[start + pos] = sv;
        else lcol[pos] = sv;
    }
    __syncthreads();
    if (!big) {
        for (int i = t; i < cnt; i += 1024) col[start + i] = lcol[i];
    }
}

// ---------- compute ----------

__device__ inline unsigned pack_bf2(float a, float b) {
    __hip_bfloat162 t;
    t.x = __float2bfloat16(a);
    t.y = __float2bfloat16(b);
    unsigned u;
    __builtin_memcpy(&u, &t, 4);
    return u;
}

__device__ inline float bf_lo(unsigned u) {
    unsigned w = u << 16; float f; __builtin_memcpy(&f, &w, 4); return f;
}
__device__ inline float bf_hi(unsigned u) {
    unsigned w = u & 0xffff0000u; float f; __builtin_memcpy(&f, &w, 4); return f;
}

// uniform-base + 32-bit byte-offset load -> global_load_dword v, voff, s[base]
__device__ inline unsigned ldu(const unsigned* p, unsigned boff) {
    return *(const unsigned*)((const char*)p + boff);
}

#define FMA16(xs0, xs1, wa, wb)                                              \
    a00 += (xs0) * (wa).x; a01 += (xs0) * (wa).y;                            \
    a02 += (xs0) * (wa).z; a03 += (xs0) * (wa).w;                            \
    a04 += (xs0) * (wb).x; a05 += (xs0) * (wb).y;                            \
    a06 += (xs0) * (wb).z; a07 += (xs0) * (wb).w;                            \
    a10 += (xs1) * (wa).x; a11 += (xs1) * (wa).y;                            \
    a12 += (xs1) * (wa).z; a13 += (xs1) * (wa).w;                            \
    a14 += (xs1) * (wb).x; a15 += (xs1) * (wb).y;                            \
    a16 += (xs1) * (wb).z; a17 += (xs1) * (wb).w;

// GEMM: 2 rows x 8 cols per thread, ALL NAMED SCALARS (hipcc does not SROA
// private arrays -> scratch).  __launch_bounds__(256,4) + unroll-4: cap 128
// VGPR (unbounded build hits 256 VGPR -> 2 waves/SIMD -> 99% latency stall).
__global__ __launch_bounds__(256, 4)
void gemm64_scaled_kernel(const float* __restrict__ X, const float* __restrict__ W,
                          const float* __restrict__ dis,
                          __hip_bfloat16* __restrict__ Y, int n) {
    __shared__ float Ws[CH * CH];
    {
        float4* w4 = (float4*)Ws;
        const float4* g4 = (const float4*)W;
        for (int i = threadIdx.x; i < CH * CH / 4; i += 256) w4[i] = g4[i];
    }
    __syncthreads();
    int t = threadIdx.x;
    int cbase = (t & 7) * 8;
    int r0 = blockIdx.x * 64 + (t >> 3) * 2;
    if (r0 >= n) return;
    int r1c = min(r0 + 1, n - 1);
    const float4* p0 = (const float4*)(X + (size_t)r0 * CH);
    const float4* p1 = (const float4*)(X + (size_t)r1c * CH);

    float a00 = 0.f, a01 = 0.f, a02 = 0.f, a03 = 0.f;
    float a04 = 0.f, a05 = 0.f, a06 = 0.f, a07 = 0.f;
    float a10 = 0.f, a11 = 0.f, a12 = 0.f, a13 = 0.f;
    float a14 = 0.f, a15 = 0.f, a16 = 0.f, a17 = 0.f;

#pragma unroll 4
    for (int k4 = 0; k4 < CH / 4; ++k4) {
        float4 xa = p0[k4];
        float4 xb = p1[k4];
        const float* wr = &Ws[(k4 * 4) * CH + cbase];
        float4 wa, wb;
        wa = *(const float4*)(wr);
        wb = *(const float4*)(wr + 4);
        FMA16(xa.x, xb.x, wa, wb)
        wa = *(const float4*)(wr + CH);
        wb = *(const float4*)(wr + CH + 4);
        FMA16(xa.y, xb.y, wa, wb)
        wa = *(const float4*)(wr + 2 * CH);
        wb = *(const float4*)(wr + 2 * CH + 4);
        FMA16(xa.z, xb.z, wa, wb)
        wa = *(const float4*)(wr + 3 * CH);
        wb = *(const float4*)(wr + 3 * CH + 4);
        FMA16(xa.w, xb.w, wa, wb)
    }

    float d0 = dis[r0];
    uint4 pk;
    pk.x = pack_bf2(a00 * d0, a01 * d0);
    pk.y = pack_bf2(a02 * d0, a03 * d0);
    pk.z = pack_bf2(a04 * d0, a05 * d0);
    pk.w = pack_bf2(a06 * d0, a07 * d0);
    *(uint4*)(Y + (size_t)r0 * CH + cbase) = pk;
    if (r0 + 1 < n) {
        float d1 = dis[r0 + 1];
        pk.x = pack_bf2(a10 * d1, a11 * d1);
        pk.y = pack_bf2(a12 * d1, a13 * d1);
        pk.z = pack_bf2(a14 * d1, a15 * d1);
        pk.w = pack_bf2(a16 * d1, a17 * d1);
        *(uint4*)(Y + (size_t)(r0 + 1) * CH + cbase) = pk;
    }
}

// R14 shfl-broadcast gather body + 32-bit saddr offsets: col[base+lane]
// loaded once per 64 edges (vector load, pipelines across batches — R15's
// scalar s_load serialized and regressed); per-edge index via __shfl; gather
// address = uniform base + 32-bit byte offset ((s<<7)|cp4) -> 1 VALU/edge
// for addressing.  16 edges in flight per batch (deg~Poisson(16): most rows
// finish in one latency round).  All __shfl sites wave-uniform (R12 bug).
#define GATHER_SHFL_BODY(XWS)                                                 \
    int beg = rs[wid];                                                        \
    int end = (wid + 1 < n) ? rs[wid + 1] : E;                                \
    unsigned cp4 = (unsigned)cp << 2;                                         \
    float accx = 0.f, accy = 0.f;                                             \
    for (int base = beg; base < end; base += 64) {                            \
        int cnt = min(64, end - base);                                        \
        int myCol = (base + lane < end) ? col[base + lane] : 0;               \
        int eb = 0;                                                           \
        for (; eb + 16 <= cnt; eb += 16) {                                    \
            unsigned o0 = ((unsigned)__shfl(myCol, eb + half, 64) << 7) | cp4;      \
            unsigned o1 = ((unsigned)__shfl(myCol, eb + 2 + half, 64) << 7) | cp4;  \
            unsigned o2 = ((unsigned)__shfl(myCol, eb + 4 + half, 64) << 7) | cp4;  \
            unsigned o3 = ((unsigned)__shfl(myCol, eb + 6 + half, 64) << 7) | cp4;  \
            unsigned o4 = ((unsigned)__shfl(myCol, eb + 8 + half, 64) << 7) | cp4;  \
            unsigned o5 = ((unsigned)__shfl(myCol, eb + 10 + half, 64) << 7) | cp4; \
            unsigned o6 = ((unsigned)__shfl(myCol, eb + 12 + half, 64) << 7) | cp4; \
            unsigned o7 = ((unsigned)__shfl(myCol, eb + 14 + half, 64) << 7) | cp4; \
            unsigned u0 = ldu((XWS), o0);                                     \
            unsigned u1 = ldu((XWS), o1);                                     \
            unsigned u2 = ldu((XWS), o2);                                     \
            unsigned u3 = ldu((XWS), o3);                                     \
            unsigned u4 = ldu((XWS), o4);                                     \
            unsigned u5 = ldu((XWS), o5);                                     \
            unsigned u6 = ldu((XWS), o6);                                     \
            unsigned u7 = ldu((XWS), o7);                                     \
            accx += bf_lo(u0) + bf_lo(u1) + bf_lo(u2) + bf_lo(u3);            \
            accy += bf_hi(u0) + bf_hi(u1) + bf_hi(u2) + bf_hi(u3);            \
            accx += bf_lo(u4) + bf_lo(u5) + bf_lo(u6) + bf_lo(u7);            \
            accy += bf_hi(u4) + bf_hi(u5) + bf_hi(u6) + bf_hi(u7);            \
        }                                                                     \
        for (; eb + 8 <= cnt; eb += 8) {                                      \
            unsigned o0 = ((unsigned)__shfl(myCol, eb + half, 64) << 7) | cp4;      \
            unsigned o1 = ((unsigned)__shfl(myCol, eb + 2 + half, 64) << 7) | cp4;  \
            unsigned o2 = ((unsigned)__shfl(myCol, eb + 4 + half, 64) << 7) | cp4;  \
            unsigned o3 = ((unsigned)__shfl(myCol, eb + 6 + half, 64) << 7) | cp4;  \
            unsigned u0 = ldu((XWS), o0);                                     \
            unsigned u1 = ldu((XWS), o1);                                     \
            unsigned u2 = ldu((XWS), o2);                                     \
            unsigned u3 = ldu((XWS), o3);                                     \
            accx += bf_lo(u0) + bf_lo(u1) + bf_lo(u2) + bf_lo(u3);            \
            accy += bf_hi(u0) + bf_hi(u1) + bf_hi(u2) + bf_hi(u3);            \
        }                                                                     \
        for (; eb + 1 < cnt; eb += 2) {                                       \
            unsigned o = ((unsigned)__shfl(myCol, eb + half, 64) << 7) | cp4; \
            unsigned u = ldu((XWS), o);                                       \
            accx += bf_lo(u); accy += bf_hi(u);                               \
        }                                                                     \
        if (eb < cnt) { /* wave-uniform: all lanes shfl, half 0 accumulates */\
            unsigned o = ((unsigned)__shfl(myCol, eb, 64) << 7) | cp4;        \
            unsigned u = ldu((XWS), o);                                       \
            if (half == 0) { accx += bf_lo(u); accy += bf_hi(u); }            \
        }                                                                     \
    }                                                                         \
    accx += __shfl_xor(accx, 32, 64);                                         \
    accy += __shfl_xor(accy, 32, 64);

// Layer-1 gather: h[wid, 2cp]=vx, h[wid, 2cp+1]=vy (fp32, dense float2/lane).
// One node per wave (max TLP — R13's 16-nodes-serial fusion was 2.3x slower).
__global__ __launch_bounds__(256)
void gather_pair_kernel(const unsigned* __restrict__ xws, const int* __restrict__ col,
                        const int* __restrict__ rs, const float* __restrict__ dis,
                        const float* __restrict__ b1, float* __restrict__ h,
                        int n, int E) {
    int wid = blockIdx.x * 4 + (threadIdx.x >> 6);
    int lane = threadIdx.x & 63;
    int cp = lane & 31;
    int half = lane >> 5;
    if (wid >= n) return;

    GATHER_SHFL_BODY(xws)

    if (half == 0) {
        float dd = dis[wid];
        unsigned us = xws[(size_t)wid * 32 + cp];
        float2 bb = ((const float2*)b1)[cp];
        float2 o;
        o.x = fmaxf(dd * (accx + bf_lo(us)) + bb.x, 0.f);
        o.y = fmaxf(dd * (accy + bf_hi(us)) + bb.y, 0.f);
        ((float2*)h)[(size_t)wid * 32 + cp] = o;  // 8B/lane, dense 256B
    }
}

// Layer-2 gather + relu + per-block LN partials.
__global__ __launch_bounds__(256)
void gather_stats_kernel(const unsigned* __restrict__ xws, const int* __restrict__ col,
                         const int* __restrict__ rs, const float* __restrict__ dis,
                         const float* __restrict__ b2, float* __restrict__ out,
                         int n, int E, float* __restrict__ sums, float* __restrict__ sqs) {
    int wid = blockIdx.x * 4 + (threadIdx.x >> 6);
    int lane = threadIdx.x & 63;
    int cp = lane & 31;
    int half = lane >> 5;
    float vx = 0.f, vy = 0.f;
    if (wid < n) {
        GATHER_SHFL_BODY(xws)
        float dd = dis[wid];
        unsigned us = xws[(size_t)wid * 32 + cp];
        float2 bb = ((const float2*)b2)[cp];
        vx = fmaxf(dd * (accx + bf_lo(us)) + bb.x, 0.f);
        vy = fmaxf(dd * (accy + bf_hi(us)) + bb.y, 0.f);
        if (half == 0) {
            float2 o; o.x = vx; o.y = vy;
            ((float2*)out)[(size_t)wid * 32 + cp] = o;
        }
    }
    float s = (half == 0) ? vx + vy : 0.f;
    float sq = (half == 0) ? vx * vx + vy * vy : 0.f;
#pragma unroll
    for (int off = 32; off > 0; off >>= 1) {
        s += __shfl_down(s, off, 64);
        sq += __shfl_down(sq, off, 64);
    }
    __shared__ float ls[4], lq[4];
    int w = threadIdx.x >> 6;
    if ((threadIdx.x & 63) == 0) { ls[w] = s; lq[w] = sq; }
    __syncthreads();
    if (threadIdx.x == 0) {
        sums[blockIdx.x] = ls[0] + ls[1] + ls[2] + ls[3];
        sqs[blockIdx.x] = lq[0] + lq[1] + lq[2] + lq[3];
    }
}

__global__ void reduce_final_kernel(const float* __restrict__ sums, const float* __restrict__ sqs,
                                    int nb, float n_total, const float* __restrict__ lnw,
                                    const float* __restrict__ lnb, float* __restrict__ so) {
    float s = 0.0f, sq = 0.0f;
    for (int i = threadIdx.x; i < nb; i += 1024) { s += sums[i]; sq += sqs[i]; }
#pragma unroll
    for (int off = 32; off > 0; off >>= 1) {
        s += __shfl_down(s, off, 64);
        sq += __shfl_down(sq, off, 64);
    }
    __shared__ float ls[16], lq[16];
    int w = threadIdx.x >> 6;
    if ((threadIdx.x & 63) == 0) { ls[w] = s; lq[w] = sq; }
    __syncthreads();
    if (threadIdx.x == 0) {
        float ts = 0.0f, tq = 0.0f;
        for (int i = 0; i < 16; ++i) { ts += ls[i]; tq += lq[i]; }
        float mean = ts / n_total;
        float var = tq / n_total - mean * mean;
        float scale = rsqrtf(var + 1e-5f) * lnw[0];
        so[0] = scale;
        so[1] = lnb[0] - mean * scale;
    }
}

__global__ void norm_kernel(float* __restrict__ x, int n4, const float* __restrict__ so) {
    int i = blockIdx.x * blockDim.x + threadIdx.x;
    if (i >= n4) return;
    float scale = so[0], off = so[1];
    float4* x4 = (float4*)x;
    float4 v = x4[i];
    v.x = v.x * scale + off;
    v.y = v.y * scale + off;
    v.z = v.z * scale + off;
    v.w = v.w * scale + off;
    x4[i] = v;
}

extern "C" void kernel_launch(void* const* d_in, const int* in_sizes, int n_in,
                              void* d_out, int out_size, void* d_ws, size_t ws_size,
                              hipStream_t stream) {
    const float* X   = (const float*)d_in[0];
    const int*   edg = (const int*)d_in[1];   // [2,E]: src row then dst row
    const float* W1  = (const float*)d_in[2];
    const float* b1  = (const float*)d_in[3];
    const float* W2  = (const float*)d_in[4];
    const float* b2  = (const float*)d_in[5];
    const float* lnw = (const float*)d_in[6];
    const float* lnb = (const float*)d_in[7];
    float* out = (float*)d_out;

    const int N  = in_sizes[0] / CH;   // 100000
    const int E  = in_sizes[1] / 2;    // 1600000
    const int NC = N * CH;             // 6.4M
    const int nNodeBlk = (N + 3) / 4;  // 25000 (4 nodes / block)
    const int nb = (N + 511) >> BSH;   // 196 buckets
    const int nblkE = (E + CHUNK - 1) / CHUNK;  // 98 edge-chunk blocks

    const int* srcp = edg;
    const int* dstp = edg + E;

    // workspace layout (4B units).  pairs (E unsigned) dead after bucket_csr;
    // h (NC floats) overlays it.
    int*   col   = (int*)d_ws;                          // E
    int*   rs    = col + E;                             // N
    float* dis   = (float*)(rs + N);                    // N
    __hip_bfloat16* xws1 = (__hip_bfloat16*)(dis + N);  // NC bf16
    __hip_bfloat16* xws2 = xws1 + NC;                   // NC bf16
    float* h     = (float*)(xws2 + NC);                 // NC floats
    unsigned* pairs = (unsigned*)h;                     // E u32 (dead before h live)
    int*   bHist = (int*)(h + NC);                      // nblkE*nb
    int*   bStart= bHist + nblkE * nb;                  // nb+1
    float* sums  = (float*)(bStart + nb + 1);           // nNodeBlk
    float* sqs   = sums + nNodeBlk;                     // nNodeBlk
    float* so    = sqs + nNodeBlk;                      // 2 {scale, offset}

    const int B = 256;
    const int nGemmBlk = (N + 63) / 64;                 // 1563

    // ---- CSR build (no global atomics, no memset) ----
    coarse_hist_kernel<<<nblkE, 1024, 0, stream>>>(dstp, bHist, E, nb);
    scan_hist_kernel<<<1, 256, 0, stream>>>(bHist, bStart, nblkE, nb);
    scatter_pairs_kernel<<<nblkE, 1024, 0, stream>>>(srcp, dstp, bHist, pairs, E, nb);
    bucket_csr_kernel<<<nb, 1024, 0, stream>>>(pairs, bStart, col, rs, dis, N, nb);
    // rs = row_start; row i spans [rs[i], rs[i+1]), last row ends at E

    // ---- layer 1 ----
    gemm64_scaled_kernel<<<nGemmBlk, B, 0, stream>>>(X, W1, dis, xws1, N);
    gather_pair_kernel<<<nNodeBlk, B, 0, stream>>>((const unsigned*)xws1, col, rs, dis,
                                                   b1, h, N, E);

    // ---- layer 2 ----
    gemm64_scaled_kernel<<<nGemmBlk, B, 0, stream>>>(h, W2, dis, xws2, N);
    gather_stats_kernel<<<nNodeBlk, B, 0, stream>>>((const unsigned*)xws2, col, rs, dis,
                                                    b2, out, N, E, sums, sqs);

    // ---- graph layernorm ----
    reduce_final_kernel<<<1, 1024, 0, stream>>>(sums, sqs, nNodeBlk, (float)NC, lnw, lnb, so);
    norm_kernel<<<(NC / 4 + B - 1) / B, B, 0, stream>>>(out, NC / 4, so);
}